// Round 7
// baseline (2253.903 us; speedup 1.0000x reference)
//
#include <hip/hip_runtime.h>
#include <math.h>

#define MU_F 0.1f
#define SHRINK_F 0.01f   // LMBD * MU
#define BN_EPS_F 1e-5f

typedef _Float16 half_t;
typedef _Float16 half8 __attribute__((ext_vector_type(8)));
typedef float f32x4 __attribute__((ext_vector_type(4)));

// async global->LDS, 16B per lane. LDS dest is wave-uniform base + lane*16.
__device__ __forceinline__ void gll16(const half_t* g, half_t* l) {
    __builtin_amdgcn_global_load_lds(
        (const __attribute__((address_space(1))) void*)g,
        (__attribute__((address_space(3))) void*)l, 16, 0, 0);
}

// counted-vmcnt wait (NO barrier: single-wave blocks; DMA completion is
// wave-visible via vmcnt) + sched fence (rule #18 hygiene).
#define VM_WAIT(N) do {                                           \
    asm volatile("s_waitcnt vmcnt(" #N ")" ::: "memory");         \
    __builtin_amdgcn_sched_barrier(0);                            \
} while (0)

// ---------------------------------------------------------------------------
// MFMA implicit-GEMM conv v7: many small BARRIER-FREE pipelines.
// Model (fits r0-r6 + m97): each barrier-synced chunk pipeline turns at a
// ~fixed ~2200-2400 cy; throughput = pipelines/CU x rate. Our grids gave
// 1.5 pipelines/CU (m97: 3 -> 37% MfmaUtil). Fix the GRID, not the loop.
//   block = 64 threads = ONE wave computing 64co x 64px.
//   grid = 392 px-tiles x 4 co-tiles = 1568 independent pipelines (~6/CU).
//   No s_barrier anywhere: the wave's own counted vmcnt orders DMA vs ds_read.
//   Staging: 8 gll16/chunk (A 4KB + B 4KB) into 3-slot LDS ring (24 KB ->
//   6 blocks/CU), lookahead 2, steady vmcnt(8), tail vmcnt(0).
//   16 MFMA : 8 ds_read_b128 per chunk (m97 per-wave ratio).
// A layout [k-chunk*9+tap][co][32]: per chunk one contiguous 4KB block.
// LDS 16B-slot swizzle: slot s holds global slot s^((row>>1)&3), applied on
// the global SOURCE (DMA dest linear) and on the ds_read address (rule 21).
// MODE 0: fwd conv stride S pad PAD; MODE 1: convT s1 (pad 1).
// edge_defer/out2F: Gram-path plumbing (round 5).
// Frag layout (16x16x32): A row=l&15, k=(l>>4)*8+j ; B col=l&15 same k;
// C/D col=l&15, row=(l>>4)*4+reg  [m89-verified].
// All outputs are 28x28 grids: NPX = 25088 = 392*64 exactly -> no px guards.
// ---------------------------------------------------------------------------
template<int KS, int S, int PAD, int MODE>
__global__ __launch_bounds__(64)
void conv_big(const half_t* __restrict__ Ag, const half_t* __restrict__ Xh,
              float* __restrict__ outF, half_t* __restrict__ outH,
              const half_t* __restrict__ auxH, const float* __restrict__ auxF,
              int CA, int Cout, int Hin, int Win, int Hout, int Wout, int ptiles,
              float alpha, float beta, float delta, int relu1,
              const float* __restrict__ pscale, const float* __restrict__ pbias,
              const float* __restrict__ aux3, int relu2,
              const half_t* __restrict__ zpg, int edge_defer,
              float* __restrict__ out2F)
{
    __shared__ __align__(16) half_t sm[3 * 4096];   // 3 slots x (A 4KB + B 4KB)

    const int ln = threadIdx.x;          // 64 threads = 1 wave
    const int co0 = blockIdx.y * 64;
    (void)ptiles;

    // bijective XCD swizzle (m204)
    int bx;
    {
        const int nwg = gridDim.x;
        const int q = nwg >> 3, r8 = nwg & 7;
        const int xcd = blockIdx.x & 7, idx = blockIdx.x >> 3;
        bx = (xcd < r8 ? xcd * (q + 1) : r8 * (q + 1) + (xcd - r8) * q) + idx;
    }
    const int p0 = bx * 64;

    const int PHW1 = Hout * Wout;

    const int r   = ln >> 2;             // 0..15: row within a 16-row DMA group
    const int s4  = ln & 3;              // 16B slot
    const int sxw = (s4 ^ ((r >> 1) & 3)) << 3;   // write-side src swizzle
    const int fr  = ln & 15, q8 = ln >> 4;
    const int sx  = (q8 ^ ((fr >> 1) & 3)) << 3;  // read-side swizzle

    const int cpt   = CA >> 5;           // k-chunks per tap (4 or 8)
    const int ntap  = KS * KS;
    const int total = ntap * cpt;        // >= 4 at every call site

    // B staging geometry: 4 groups of 16 px rows (row = j*16 + r)
    int bph[4], bpw[4]; size_t bnb[4];
#pragma unroll
    for (int j = 0; j < 4; ++j) {
        int px = p0 + j * 16 + r;        // always < 25088 (exact tiling)
        int n2 = px / PHW1; int rem = px - n2 * PHW1;
        int ph = rem / Wout;
        bph[j] = ph; bpw[j] = rem - ph * Wout;
        bnb[j] = (size_t)n2 * Hin * Win;
    }

    // issue one chunk: A 4KB (4 gll16) + B 4KB (4 gll16) into dst slot
    auto issue = [&](int flat, half_t* dst) {
        int cc, ti;
        if (KS == 1) { cc = flat; ti = 0; }
        else         { cc = (flat * 57) >> 9; ti = flat - 9 * cc; }  // /9, flat<72
        const int kh = (KS == 3) ? ((ti * 11) >> 5) : 0;             // /3, ti<9
        const int kw = (KS == 3) ? (ti - 3 * kh) : 0;
        const int c0 = cc << 5;
        const size_t abase = ((size_t)flat * Cout + co0) * 32;
#pragma unroll
        for (int j = 0; j < 4; ++j)
            gll16(Ag + abase + (size_t)(j * 16 + r) * 32 + sxw, dst + j * 512 + ln * 8);
#pragma unroll
        for (int j = 0; j < 4; ++j) {
            int hh, ww2;
            if (MODE == 0) { hh = bph[j] * S - PAD + kh; ww2 = bpw[j] * S - PAD + kw; }
            else           { hh = bph[j] + PAD - kh;     ww2 = bpw[j] + PAD - kw; }
            bool ok = (unsigned)hh < (unsigned)Hin && (unsigned)ww2 < (unsigned)Win;
            const half_t* src = ok
                ? Xh + (bnb[j] + (size_t)(hh * Win + ww2)) * CA + c0 + sxw
                : zpg;
            gll16(src, dst + 2048 + j * 512 + ln * 8);
        }
    };

    f32x4 acc[4][4] = {};

    // prologue: chunks 0,1 in flight (16 ops); wait chunk 0 (8 newest remain)
    issue(0, sm);
    issue(1, sm + 4096);
    VM_WAIT(8);

    int si = 0;
    for (int k = 0; k < total; ++k) {
        half_t* cur = sm + si * 4096;
        if (k + 2 < total) {
            int s2 = si + 2; if (s2 >= 3) s2 -= 3;
            issue(k + 2, sm + s2 * 4096);
        }
        half8 fa[4], fb[4];
#pragma unroll
        for (int m = 0; m < 4; ++m)
            fa[m] = *(const half8*)(cur + (m * 16 + fr) * 32 + sx);
#pragma unroll
        for (int t2 = 0; t2 < 4; ++t2)
            fb[t2] = *(const half8*)(cur + 2048 + (t2 * 16 + fr) * 32 + sx);
#pragma unroll
        for (int m = 0; m < 4; ++m)
#pragma unroll
            for (int t2 = 0; t2 < 4; ++t2)
                acc[m][t2] = __builtin_amdgcn_mfma_f32_16x16x32_f16(fa[m], fb[t2], acc[m][t2], 0, 0, 0);
        // end-of-iter: chunk k+1 must be resident for next iter.
        // outstanding: (k+2<total ? 8 : 0) for chunk k+2, + 8 for chunk k+1.
        if (k + 2 < total)      VM_WAIT(8);
        else if (k + 1 < total) VM_WAIT(0);
        si = (si == 2) ? 0 : si + 1;
    }

    // epilogue: 64co x 64px per block; each lane 16 outputs
    const int rg = q8;
#pragma unroll
    for (int t = 0; t < 4; ++t) {
        int px = p0 + t * 16 + fr;
        int n2 = px / PHW1; int rem = px - n2 * PHW1;
        int oh = rem / Wout, ow = rem - oh * Wout;
        size_t ghwc = ((size_t)(n2 * Hout + oh) * Wout + ow) * Cout;
        bool defer = edge_defer && (oh == 0 || ow == 0);
#pragma unroll
        for (int m = 0; m < 4; ++m) {
#pragma unroll
            for (int rr = 0; rr < 4; ++rr) {
                int co_l = co0 + m * 16 + rg * 4 + rr;
                size_t fidx = ((size_t)(n2 * Cout + co_l) * Hout + oh) * Wout + ow;
                float av = alpha * acc[m][t][rr];
                if (out2F) out2F[fidx] = av;
                float v = av + delta;
                if (auxH) v += beta * (float)auxH[ghwc + co_l];
                if (auxF) v += beta * auxF[fidx];
                if (!defer) {
                    if (relu1) v = fmaxf(v, 0.f);
                    if (pscale) v = pscale[co_l] * v + pbias[co_l];
                    if (aux3) v += aux3[fidx];
                    if (relu2) v = fmaxf(v, 0.f);
                }
                if (outH) outH[ghwc + co_l] = (half_t)v;
                else      outF[fidx] = v;
            }
        }
    }
}

// pack weights into the contiguous MFMA layout [ci-chunk*KT+tap][co][32ci]
// (and transpose variant [co-chunk*KT+tap][ci][32co] for convT).
template<int KT>
__global__ __launch_bounds__(256)
void pack_w(const float* __restrict__ W, half_t* __restrict__ Wh,
            half_t* __restrict__ WTh, int Cin, int Cout, int do_norm)
{
    __shared__ float red[256];
    int co = blockIdx.x, tid = threadIdx.x;
    int CK = Cin * KT;
    const float* w = W + (size_t)co * CK;
    float inv = 1.f;
    if (do_norm) {
        float s = 0.f;
        for (int i = tid; i < CK; i += 256) { float v = w[i]; s += v * v; }
        red[tid] = s; __syncthreads();
        for (int o = 128; o > 0; o >>= 1) {
            if (tid < o) red[tid] += red[tid + o];
            __syncthreads();
        }
        inv = 1.f / (sqrtf(red[0]) + 1e-12f);
    }
    for (int i = tid; i < CK; i += 256) {
        int ci = i / KT, tap = i - ci * KT;
        half_t h = (half_t)(w[i] * inv);
        Wh[(((size_t)(ci >> 5) * KT + tap) * Cout + co) * 32 + (ci & 31)] = h;
        if (WTh) WTh[(((size_t)(co >> 5) * KT + tap) * Cin + ci) * 32 + (co & 31)] = h;
    }
}

// ---------------------------------------------------------------------------
// Gram precompute (round 5): Gp in the contiguous conv layout
// [b-chunk*9+tap][co][32b]; edge tensors unchanged.
// ---------------------------------------------------------------------------
__global__ __launch_bounds__(256)
void gram_kernel(const half_t* __restrict__ Wh, half_t* __restrict__ Gp,
                 half_t* __restrict__ ChT, half_t* __restrict__ CwT,
                 half_t* __restrict__ CcT)
{
    // Wh here is the raw [co][tap][ci] layout (Wr1), ci<128, normalized.
    __shared__ float Wa[9 * 128];
    int co = blockIdx.x, b = threadIdx.x;
    for (int i = b; i < 9 * 128; i += 256) Wa[i] = (float)Wh[(size_t)co * 9 * 128 + i];
    __syncthreads();
    const half_t* Wb = Wh + (size_t)b * 9 * 128;
    auto dot = [&](int tA, int tB) {
        float s = 0.f;
        for (int c = 0; c < 128; ++c) s += Wa[tA * 128 + c] * (float)Wb[tB * 128 + c];
        return s;
    };
    auto lo = [](int t) { return (t == 2) ? 2 : 0; };
    auto hi = [](int t) { return (t == 1) ? 3 : ((t == 2) ? 3 : 1); };
    for (int th = 0; th < 3; ++th)
        for (int tw = 0; tw < 3; ++tw) {
            float s = 0.f;
            for (int kh = lo(th); kh < hi(th); ++kh)
                for (int kw = lo(tw); kw < hi(tw); ++kw)
                    s += dot(kh * 3 + kw, (kh + 2 - 2 * th) * 3 + (kw + 2 - 2 * tw));
            Gp[(((size_t)(b >> 5) * 9 + th * 3 + tw) * 256 + co) * 32 + (b & 31)] = (half_t)s;
        }
    for (int tw = 0; tw < 3; ++tw) {
        float s = 0.f, s2 = 0.f;
        for (int k = lo(tw); k < hi(tw); ++k) {
            s  += dot(k, k + 2 - 2 * tw);
            s2 += dot(k * 3, (k + 2 - 2 * tw) * 3);
        }
        ChT[((size_t)tw * 256 + b) * 256 + co] = (half_t)s;
        CwT[((size_t)tw * 256 + b) * 256 + co] = (half_t)s2;
    }
    CcT[(size_t)b * 256 + co] = (half_t)dot(0, 0);
}

// raw [co][tap][ci] normalized pack (input for gram_kernel only)
__global__ __launch_bounds__(256)
void pack_raw(const float* __restrict__ W, half_t* __restrict__ Wr, int CK)
{
    __shared__ float red[256];
    int co = blockIdx.x, tid = threadIdx.x;
    const float* w = W + (size_t)co * CK;
    float s = 0.f;
    for (int i = tid; i < CK; i += 256) { float v = w[i]; s += v * v; }
    red[tid] = s; __syncthreads();
    for (int o = 128; o > 0; o >>= 1) {
        if (tid < o) red[tid] += red[tid + o];
        __syncthreads();
    }
    float inv = 1.f / (sqrtf(red[0]) + 1e-12f);
    for (int i = tid; i < CK; i += 256) {
        int ci = i / 9, tap = i - ci * 9;
        Wr[((size_t)co * 9 + tap) * (CK / 9) + ci] = (half_t)(w[i] * inv);
    }
}

__global__ __launch_bounds__(256)
void edge_fix(const half_t* __restrict__ a, half_t* out,
              const half_t* __restrict__ ChT, const half_t* __restrict__ CwT,
              const half_t* __restrict__ CcT,
              const float* __restrict__ ps, const float* __restrict__ pb)
{
    int i = blockIdx.x, n = blockIdx.y, co = threadIdx.x;
    int oh, ow;
    if (i < 28) { oh = 0; ow = i; } else { oh = i - 27; ow = 0; }
    float corr = 0.f;
    if (oh == 0) {
        for (int kw = 0; kw < 3; ++kw) {
            int pw = ow - 1 + kw;
            if ((unsigned)pw < 28u) {
                const half_t* ap = a + ((size_t)(n * 28 + 0) * 28 + pw) * 256;
                const half_t* cp = ChT + (size_t)kw * 256 * 256 + co;
                for (int b2 = 0; b2 < 256; ++b2)
                    corr += (float)cp[(size_t)b2 * 256] * (float)ap[b2];
            }
        }
    }
    if (ow == 0) {
        for (int kh = 0; kh < 3; ++kh) {
            int ph = oh - 1 + kh;
            if ((unsigned)ph < 28u) {
                const half_t* ap = a + ((size_t)(n * 28 + ph) * 28 + 0) * 256;
                const half_t* cp = CwT + (size_t)kh * 256 * 256 + co;
                for (int b2 = 0; b2 < 256; ++b2)
                    corr += (float)cp[(size_t)b2 * 256] * (float)ap[b2];
            }
        }
    }
    if (oh == 0 && ow == 0) {
        const half_t* ap = a + ((size_t)(n * 28) * 28) * 256;
        for (int b2 = 0; b2 < 256; ++b2)
            corr -= (float)CcT[(size_t)b2 * 256 + co] * (float)ap[b2];
    }
    size_t idx = ((size_t)(n * 28 + oh) * 28 + ow) * 256 + co;
    float v = (float)out[idx] + MU_F * corr;
    v = fmaxf(v, 0.f);
    if (ps) v = ps[co] * v + pb[co];
    out[idx] = (half_t)v;
}

__global__ __launch_bounds__(256)
void tx_kernel(const float* __restrict__ x, half_t* __restrict__ xTh)
{
    __shared__ __align__(16) half_t tl[56 * 136];
    int h = blockIdx.x, n = blockIdx.y, tid = threadIdx.x;
    for (int it = 0; it < 28; ++it) {
        int id = tid + it * 256;
        int c = id / 56, w0 = id - c * 56;
        tl[w0 * 136 + c] = (half_t)x[(((size_t)n * 128 + c) * 56 + h) * 56 + w0];
    }
    __syncthreads();
    if (tid < 224) {
        int w0 = tid >> 2, part = tid & 3;
        size_t base = (((size_t)n * 56 + h) * 56 + w0) * 128 + part * 32;
#pragma unroll
        for (int j = 0; j < 4; ++j)
            *(half8*)(xTh + base + j * 8) = *(const half8*)(tl + w0 * 136 + part * 32 + j * 8);
    }
}

__global__ __launch_bounds__(256)
void comb_kernel(const half_t* __restrict__ c, const half_t* __restrict__ p,
                 half_t* __restrict__ a, float w1, float w2, int n8)
{
    int i = blockIdx.x * 256 + threadIdx.x;
    if (i >= n8) return;
    half8 cv = ((const half8*)c)[i];
    half8 pv = ((const half8*)p)[i];
    half8 rres;
#pragma unroll
    for (int j = 0; j < 8; ++j) rres[j] = (half_t)(w1 * (float)cv[j] + w2 * (float)pv[j]);
    ((half8*)a)[i] = rres;
}

__global__ __launch_bounds__(256)
void bn_prep_kernel(const float* __restrict__ g, const float* __restrict__ b,
                    const float* __restrict__ m, const float* __restrict__ v,
                    float* __restrict__ s, float* __restrict__ t, int C)
{
    int i = blockIdx.x * 256 + threadIdx.x;
    if (i < C) {
        float sc = g[i] * rsqrtf(v[i] + BN_EPS_F);
        s[i] = sc; t[i] = b[i] - m[i] * sc;
    }
}

__global__ __launch_bounds__(128)
void zfill_kernel(half_t* __restrict__ p)
{
    p[threadIdx.x] = (half_t)0.f;
}

extern "C" void kernel_launch(void* const* d_in, const int* in_sizes, int n_in,
                              void* d_out, int out_size, void* d_ws, size_t ws_size,
                              hipStream_t stream)
{
    (void)in_sizes; (void)n_in; (void)out_size;
    const float* x    = (const float*)d_in[0];
    const float* W1   = (const float*)d_in[1];
    const float* W2   = (const float*)d_in[2];
    const float* Wsc  = (const float*)d_in[3];
    const float* bn1g = (const float*)d_in[4];
    const float* bn1b = (const float*)d_in[5];
    const float* bn1m = (const float*)d_in[6];
    const float* bn1v = (const float*)d_in[7];
    const float* bn2g = (const float*)d_in[8];
    const float* bn2b = (const float*)d_in[9];
    const float* bn2m = (const float*)d_in[10];
    const float* bn2v = (const float*)d_in[11];
    const float* bscg = (const float*)d_in[12];
    const float* bscb = (const float*)d_in[13];
    const float* bscm = (const float*)d_in[14];
    const float* bscv = (const float*)d_in[15];

    const size_t NB = (size_t)32 * 256 * 28 * 28;
    const size_t NX = (size_t)32 * 128 * 56 * 56;

    char* base = (char*)d_ws;
    size_t off = 0;
    auto alloc = [&](size_t nbytes) -> void* {
        void* r = base + off;
        off = (off + nbytes + 255) & ~(size_t)255;
        return r;
    };
    half_t* Wh1  = (half_t*)alloc(294912 * 2);
    half_t* Wr1  = (half_t*)alloc(294912 * 2);   // raw [co][tap][ci] for gram
    half_t* Wh2  = (half_t*)alloc(589824 * 2);
    half_t* WTh2 = (half_t*)alloc(589824 * 2);
    half_t* Wsch = (half_t*)alloc(32768 * 2);
    half_t* Gph  = (half_t*)alloc(589824 * 2);
    half_t* ChT  = (half_t*)alloc(196608 * 2);
    half_t* CwT  = (half_t*)alloc(196608 * 2);
    half_t* CcT  = (half_t*)alloc(65536 * 2);
    float* bn1s = (float*)alloc(256 * 4);  float* bn1t = (float*)alloc(256 * 4);
    float* bn2s = (float*)alloc(256 * 4);  float* bn2t = (float*)alloc(256 * 4);
    float* bscs = (float*)alloc(256 * 4);  float* bsct = (float*)alloc(256 * 4);
    half_t* zpg  = (half_t*)alloc(256);
    half_t* xTh  = (half_t*)alloc(NX * 2);
    half_t* Pa   = (half_t*)alloc(NB * 2);
    half_t* Pb   = (half_t*)alloc(NB * 2);
    half_t* Pc   = (half_t*)alloc(NB * 2);
    half_t* Py   = (half_t*)alloc(NB * 2);
    half_t* r28h = (half_t*)alloc(NB * 2);
    float*  scF  = (float*)alloc(NB * 4);
    if (off > ws_size) return;

    float*  cxF = (float*)Py;    // fp32 NCHW cache, over Py+r28h (dead in stage A)
    half_t* Pd  = (half_t*)xTh;  // stage-B temp, over xTh (dead in stage B)

    float* outp = (float*)d_out;

    double t = 1.0; float al[3];
    for (int i = 0; i < 3; ++i) {
        double tn = (1.0 + sqrt(1.0 + 4.0 * t * t)) / 2.0;
        al[i] = (float)((t - 1.0) / tn); t = tn;
    }

    const dim3 blk(256);
    const dim3 cblk(64);           // ONE wave per block
    const dim3 gB(392, 4, 1);      // 392 px-tiles x 4 co-tiles = 1568 pipelines
    const dim3 gE(55, 32, 1);
    const int n8 = (int)(NB / 8);
    const dim3 gC((n8 + 255) / 256);
    const float* NF = nullptr;
    const half_t* NH = nullptr;
    float* NFo = nullptr;
    half_t* NHo = nullptr;

    pack_w<9><<<256, blk, 0, stream>>>(W1, Wh1, nullptr, 128, 256, 1);
    pack_raw<<<256, blk, 0, stream>>>(W1, Wr1, 128 * 9);
    pack_w<9><<<256, blk, 0, stream>>>(W2, Wh2, WTh2, 256, 256, 1);
    pack_w<1><<<256, blk, 0, stream>>>(Wsc, Wsch, nullptr, 128, 256, 0);
    gram_kernel<<<256, blk, 0, stream>>>(Wr1, Gph, ChT, CwT, CcT);
    bn_prep_kernel<<<1, blk, 0, stream>>>(bn1g, bn1b, bn1m, bn1v, bn1s, bn1t, 256);
    bn_prep_kernel<<<1, blk, 0, stream>>>(bn2g, bn2b, bn2m, bn2v, bn2s, bn2t, 256);
    bn_prep_kernel<<<1, blk, 0, stream>>>(bscg, bscb, bscm, bscv, bscs, bsct, 256);
    zfill_kernel<<<1, dim3(128), 0, stream>>>(zpg);
    tx_kernel<<<dim3(56, 32), blk, 0, stream>>>(x, xTh);

    // ============ Stage A: dict_conv(x, W1, stride 2) — Gram form ==========
    conv_big<3,2,1,0><<<gB, cblk, 0, stream>>>(Wh1, xTh, NFo, Pa, NH, NF,
        128, 256, 56, 56, 28, 28, 392, MU_F, 0.f, -SHRINK_F, 1, NF, NF, NF, 0, zpg, 0, cxF);
    conv_big<1,2,0,0><<<gB, cblk, 0, stream>>>(Wsch, xTh, scF, NHo, NH, NF,
        128, 256, 56, 56, 28, 28, 392, 1.f, 0.f, 0.f, 0, bscs, bsct, NF, 0, zpg, 0, NFo);

    conv_big<3,1,1,0><<<gB, cblk, 0, stream>>>(Gph, Pa, NFo, Pb, Pa, cxF,
        256, 256, 28, 28, 28, 28, 392, -MU_F, 1.f, -SHRINK_F, 1, NF, NF, NF, 0, zpg, 1, NFo);
    edge_fix<<<gE, blk, 0, stream>>>(Pa, Pb, ChT, CwT, CcT, NF, NF);

    comb_kernel<<<gC, blk, 0, stream>>>(Pb, Pa, Pc, 1.f + al[1], -al[1], n8);
    conv_big<3,1,1,0><<<gB, cblk, 0, stream>>>(Gph, Pc, NFo, Pa, Pc, cxF,
        256, 256, 28, 28, 28, 28, 392, -MU_F, 1.f, -SHRINK_F, 1, NF, NF, NF, 0, zpg, 1, NFo);
    edge_fix<<<gE, blk, 0, stream>>>(Pc, Pa, ChT, CwT, CcT, NF, NF);

    comb_kernel<<<gC, blk, 0, stream>>>(Pa, Pb, Pc, 1.f + al[2], -al[2], n8);
    conv_big<3,1,1,0><<<gB, cblk, 0, stream>>>(Gph, Pc, NFo, Pb, Pc, cxF,
        256, 256, 28, 28, 28, 28, 392, -MU_F, 1.f, -SHRINK_F, 1, bn1s, bn1t, NF, 0, zpg, 1, NFo);
    edge_fix<<<gE, blk, 0, stream>>>(Pc, Pb, ChT, CwT, CcT, bn1s, bn1t);

    // ================= Stage B: dict_conv(y1=Pb, W2, stride 1) =============
    conv_big<3,1,1,0><<<gB, cblk, 0, stream>>>(Wh2, Pb, NFo, Pa, NH, NF,
        256, 256, 28, 28, 28, 28, 392, MU_F, 0.f, -SHRINK_F, 1, NF, NF, NF, 0, zpg, 0, NFo);

    conv_big<3,1,1,1><<<gB, cblk, 0, stream>>>(WTh2, Pa, NFo, r28h, Pb, NF,
        256, 256, 28, 28, 28, 28, 392, -1.f, 1.f, 0.f, 0, NF, NF, NF, 0, zpg, 0, NFo);
    conv_big<3,1,1,0><<<gB, cblk, 0, stream>>>(Wh2, r28h, NFo, Pd, Pa, NF,
        256, 256, 28, 28, 28, 28, 392, MU_F, 1.f, -SHRINK_F, 1, NF, NF, NF, 0, zpg, 0, NFo);

    comb_kernel<<<gC, blk, 0, stream>>>(Pd, Pa, Pc, 1.f + al[1], -al[1], n8);
    conv_big<3,1,1,1><<<gB, cblk, 0, stream>>>(WTh2, Pc, NFo, r28h, Pb, NF,
        256, 256, 28, 28, 28, 28, 392, -1.f, 1.f, 0.f, 0, NF, NF, NF, 0, zpg, 0, NFo);
    conv_big<3,1,1,0><<<gB, cblk, 0, stream>>>(Wh2, r28h, NFo, Pa, Pc, NF,
        256, 256, 28, 28, 28, 28, 392, MU_F, 1.f, -SHRINK_F, 1, NF, NF, NF, 0, zpg, 0, NFo);

    comb_kernel<<<gC, blk, 0, stream>>>(Pa, Pd, Pc, 1.f + al[2], -al[2], n8);
    conv_big<3,1,1,1><<<gB, cblk, 0, stream>>>(WTh2, Pc, NFo, r28h, Pb, NF,
        256, 256, 28, 28, 28, 28, 392, -1.f, 1.f, 0.f, 0, NF, NF, NF, 0, zpg, 0, NFo);
    conv_big<3,1,1,0><<<gB, cblk, 0, stream>>>(Wh2, r28h, outp, NHo, Pc, NF,
        256, 256, 28, 28, 28, 28, 392, MU_F, 1.f, -SHRINK_F, 1, bn2s, bn2t, scF, 1, zpg, 0, NFo);
}